// Round 17
// baseline (46.643 us; speedup 1.0000x reference)
//
#include <hip/hip_runtime.h>
#include <hip/hip_bf16.h>
#include <math.h>

// ---------------------------------------------------------------------------
// QuanvolutionAutoencoder, B=4096, fp32 in/out.
//   feats = quanv(x, theta)              [4096,784]
//   h1    = relu(feats @ W1 + b1)        [4096,512]
//   lat   = h1 @ W2 + b2                 [4096,32]    } fused row-local
//   h2    = relu(lat @ W3 + b3)          [4096,512]   } (mlp_mid kernel)
//   out   = sigmoid(h2 @ W4 + b4)        [4096,784]
// 4 dispatches: prep (quanv in-register gates + HW trig, pad-fold), GEMM1
// (8-wave 64x64 BK=128), mlp_mid (+W4 transpose), GEMM4 (8-wave BK=64).
// ---------------------------------------------------------------------------

#define BATCH   4096
#define NPATCH  196
#define FEATDIM 784
#define KP1     832     // K for GEMM1 padded to 13*64 (final 64 via half step)
#define NP4     832     // N for GEMM4 padded to 13*64

typedef __bf16 b8 __attribute__((ext_vector_type(8)));
typedef float  f4 __attribute__((ext_vector_type(4)));

__device__ __forceinline__ unsigned short f2bf(float f) {
    unsigned u = __float_as_uint(f);
    u += 0x7FFF + ((u >> 16) & 1);          // round-to-nearest-even
    return (unsigned short)(u >> 16);
}

__device__ __forceinline__ void gload16(const void* g, void* l) {
    __builtin_amdgcn_global_load_lds(
        (const __attribute__((address_space(1))) unsigned int*)g,
        (__attribute__((address_space(3))) unsigned int*)l, 16, 0, 0);
}

// sin(x/2), cos(x/2) via hardware v_sin_f32/v_cos_f32 (D = sin(S0*2pi)).
// rev = x * 1/(4pi); all inputs here give rev in [0, 0.5) -> no reduction.
#define REV4PI 0.07957747154594767f
__device__ __forceinline__ float hsin2(float x) {
    return __builtin_amdgcn_sinf(x * REV4PI);
}
__device__ __forceinline__ float hcos2(float x) {
    return __builtin_amdgcn_cosf(x * REV4PI);
}

// ---------------------------------------------------------------------------
// Prep kernel block roles:
//   [0, 3136)        quanv -> featsB (bf16, pitch 832); p<6 also writes pads
//   [3136, 3240)     W1 transpose (LDS-tiled): W1B[n*832+k], pads zeroed
//   [3240, 3304)     W2T[n*512+k] = bf16(W2[k*32+n])       (32x512)
//   [3304, 3368)     W3T[n*32+k]  = bf16(W3[k*512+n])      (512x32)
// (W4 transpose piggybacks on mlp_mid.)
// ---------------------------------------------------------------------------
#define Q_END   3136
#define T1_END  3240
#define W2T_END 3304
#define W3T_END 3368

__global__ __launch_bounds__(256)
void prep_kernel(const float* __restrict__ x, const float* __restrict__ theta,
                 const float* __restrict__ W1, const float* __restrict__ W2,
                 const float* __restrict__ W3,
                 unsigned short* __restrict__ featsB,
                 unsigned short* __restrict__ W1B,
                 unsigned short* __restrict__ W2T,
                 unsigned short* __restrict__ W3T) {
    __shared__ float shm[64 * 65];          // 16.6 KB; used by transpose role
    const int bid = blockIdx.x;
    const int tid = threadIdx.x;

    if (bid < Q_END) {
        // ------ quanvolution: in-register gates, HW transcendentals ------
        int n = bid * 256 + tid;
        int b = n / NPATCH;
        int p = n % NPATCH;
        int r = p / 14;
        int c = p % 14;

        const float* img = x + (size_t)b * FEATDIM;
        float2 p0 = *(const float2*)&img[(2 * r) * 28 + 2 * c];
        float2 p1 = *(const float2*)&img[(2 * r + 1) * 28 + 2 * c];

        float a0c = hcos2(p0.x), a0s = hsin2(p0.x);
        float a1c = hcos2(p0.y), a1s = hsin2(p0.y);
        float a2c = hcos2(p1.x), a2s = hsin2(p1.x);
        float a3c = hcos2(p1.y), a3s = hsin2(p1.y);

        // product state |psi> via 4->8->16 tree (wire w -> bit 3-w)
        float w01[4], w012[8], stv[16];
        w01[0] = a0c * a1c; w01[1] = a0c * a1s;
        w01[2] = a0s * a1c; w01[3] = a0s * a1s;
#pragma unroll
        for (int i = 0; i < 4; ++i) {
            w012[2 * i]     = w01[i] * a2c;
            w012[2 * i + 1] = w01[i] * a2s;
        }
#pragma unroll
        for (int i = 0; i < 8; ++i) {
            stv[2 * i]     = w012[i] * a3c;
            stv[2 * i + 1] = w012[i] * a3s;
        }

        // gate angles (uniform across threads)
        float ct[8], st[8];
#pragma unroll
        for (int k = 0; k < 8; ++k) {
            float th = theta[k];
            ct[k] = hcos2(th);
            st[k] = hsin2(th);
        }

        // PAIRS = [(0,1),(1,2),(2,3),(3,0),(0,2),(1,3),(2,0),(3,1)], bit=3-wire
        const int cb[8] = {3, 2, 1, 0, 3, 2, 1, 0};
        const int tb[8] = {2, 1, 0, 3, 1, 0, 3, 2};
#pragma unroll
        for (int k = 0; k < 8; ++k) {
            const int cm = 1 << cb[k], tm = 1 << tb[k];
#pragma unroll
            for (int s = 0; s < 16; ++s) {
                if ((s & cm) && !(s & tm)) {    // compile-time after unroll
                    float v0 = stv[s], v1 = stv[s | tm];
                    stv[s]      = ct[k] * v0 - st[k] * v1;
                    stv[s | tm] = st[k] * v0 + ct[k] * v1;
                }
            }
        }

        float m0 = 0.f, m1 = 0.f, m2 = 0.f, m3 = 0.f;
#pragma unroll
        for (int s = 0; s < 16; ++s) {
            float pr = stv[s] * stv[s];
            m0 += (s & 8) ? -pr : pr;
            m1 += (s & 4) ? -pr : pr;
            m2 += (s & 2) ? -pr : pr;
            m3 += (s & 1) ? -pr : pr;
        }
        ushort4 o;
        o.x = f2bf(m0); o.y = f2bf(m1); o.z = f2bf(m2); o.w = f2bf(m3);
        *(ushort4*)&featsB[(size_t)b * KP1 + p * 4] = o;
        // fold pad-zeroing: cols 784..831 of row b (6 float4), by p<6
        if (p < 6)
            *(float4*)&featsB[(size_t)b * KP1 + FEATDIM + p * 8] =
                make_float4(0.f, 0.f, 0.f, 0.f);
    } else if (bid < T1_END) {
        // -- W1 [784][512] -> W1B [512][832] (transpose, pads zeroed) --
        float (*T)[65] = (float (*)[65])shm;
        int bb = bid - Q_END;               // 13 kt x 8 nt
        int k0 = (bb / 8) * 64, n0 = (bb % 8) * 64;
        int rr = tid >> 6, c = tid & 63;
#pragma unroll
        for (int i = 0; i < 16; ++i) {
            int r = i * 4 + rr;
            if (k0 + r < FEATDIM) T[r][c] = W1[(size_t)(k0 + r) * 512 + n0 + c];
        }
        __syncthreads();
#pragma unroll
        for (int i = 0; i < 16; ++i) {
            int nn = i * 4 + rr;
            unsigned short v = (k0 + c < FEATDIM) ? f2bf(T[c][nn]) : (unsigned short)0;
            W1B[(size_t)(n0 + nn) * KP1 + k0 + c] = v;
        }
    } else if (bid < W2T_END) {
        // -- W2T[n*512+k] = bf16(W2[k*32+n]), n<32, k<512 --
        int idx = (bid - T1_END) * 256 + tid;   // 16384
        int n = idx >> 9, k = idx & 511;
        W2T[idx] = f2bf(W2[(size_t)k * 32 + n]);
    } else {
        // -- W3T[n*32+k] = bf16(W3[k*512+n]), n<512, k<32 --
        int idx = (bid - W2T_END) * 256 + tid;  // 16384
        int n = idx >> 5, k = idx & 31;
        W3T[idx] = f2bf(W3[(size_t)k * 512 + n]);
    }
}

// ---------------------------------------------------------------------------
// bf16 MFMA GEMM, tile 64x64, NW waves (NW*64 threads), BK = NH*64.
//   NW=4: waves 2M x 2N, 32x32/wave (MF=2).
//   NW=8: waves 4M x 2N, 16x32/wave (MF=1) -- 2x waves/SIMD (R14-proven).
// dbuf LDS, gload16 with XOR-swizzled source, XCD-chunked blockIdx.
// khalf: final K-step half (NH=2 only). ACT: 1=relu, 2=sigmoid.
// OUT_BF16: 1 bf16 / 0 fp32 (nt store).
// ---------------------------------------------------------------------------
template <int NW, int MF, int NH, int ACT, int OUT_BF16>
__global__ __launch_bounds__(NW * 64)
void gemm_mfma(const unsigned short* __restrict__ A,   // [M][lda] bf16
               const unsigned short* __restrict__ BT,  // [Npad][ldb] bf16
               const float* __restrict__ bias,         // [Nlog] fp32
               void* __restrict__ C,                   // [M][ldc]
               int lda, int ldb, int ldc, int Nlog, int nkt, int khalf,
               int gx) {
    __shared__ __align__(16) unsigned short As[2][NH][64 * 64];
    __shared__ __align__(16) unsigned short Bs[2][NH][64 * 64];

    const int nwg = gridDim.x;
    const int d   = blockIdx.x;
    const int tile = (d & 7) * (nwg >> 3) + (d >> 3);
    const int bx = tile % gx;
    const int by = tile / gx;

    const int t  = threadIdx.x;
    const int w  = t >> 6;
    const int l  = t & 63;
    const int wm = w >> 1;                  // M index (0..NW/2-1)
    const int wn = w & 1;                   // N half
    const int row0 = by * 64;
    const int col0 = bx * 64;

    const int sr = l >> 3;
    const int sc = ((l & 7) ^ sr) * 8;
    const unsigned short* Ab = A  + (size_t)(row0 + w * 8 + sr) * lda + sc;
    const unsigned short* Bb = BT + (size_t)(col0 + w * 8 + sr) * ldb + sc;

    const int q  = l >> 4;
    const int lx = l & 15;
    const int sx = l & 7;
    const int coff[2] = { ((0 + q) ^ sx) * 16, ((4 + q) ^ sx) * 16 };

    f4 acc[MF][2];
#pragma unroll
    for (int m = 0; m < MF; ++m)
#pragma unroll
        for (int n = 0; n < 2; ++n) acc[m][n] = (f4)0.f;

    constexpr int ITS = 64 / (NW * 8);      // staging passes over 64 rows

    auto stage = [&](int bi, int kt) {
        const int nh = (NH == 2 && khalf && kt == nkt - 1) ? 1 : NH;
        for (int h = 0; h < nh; ++h) {
            const size_t k0 = (size_t)kt * (NH * 64) + h * 64;
            char* la = (char*)&As[bi][h][0] + w * 1024;
            char* lb = (char*)&Bs[bi][h][0] + w * 1024;
#pragma unroll
            for (int it = 0; it < ITS; ++it) {
                gload16(Ab + (size_t)(it * NW * 8) * lda + k0, la + it * NW * 1024);
                gload16(Bb + (size_t)(it * NW * 8) * ldb + k0, lb + it * NW * 1024);
            }
        }
    };

    auto compute = [&](int bi, int kt) {
        const int nh = (NH == 2 && khalf && kt == nkt - 1) ? 1 : NH;
        for (int h = 0; h < nh; ++h) {
            const char* la = (const char*)&As[bi][h][0];
            const char* lb = (const char*)&Bs[bi][h][0];
#pragma unroll
            for (int kk = 0; kk < 2; ++kk) {
                const int co = coff[kk];
                b8 a[MF], bf[2];
#pragma unroll
                for (int m = 0; m < MF; ++m)
                    a[m] = *(const b8*)(la + (wm * MF * 16 + m * 16 + lx) * 128 + co);
#pragma unroll
                for (int n = 0; n < 2; ++n)
                    bf[n] = *(const b8*)(lb + (wn * 32 + n * 16 + lx) * 128 + co);
#pragma unroll
                for (int m = 0; m < MF; ++m)
#pragma unroll
                    for (int n = 0; n < 2; ++n)
                        acc[m][n] = __builtin_amdgcn_mfma_f32_16x16x32_bf16(
                            a[m], bf[n], acc[m][n], 0, 0, 0);
            }
        }
    };

    stage(0, 0);
    __syncthreads();
    for (int kt = 0; kt < nkt; ++kt) {
        if (kt + 1 < nkt) stage((kt + 1) & 1, kt + 1);
        compute(kt & 1, kt);
        __syncthreads();
    }

#pragma unroll
    for (int n = 0; n < 2; ++n) {
        int col = col0 + wn * 32 + n * 16 + lx;
        if (col >= Nlog) continue;
        float bv = bias[col];
#pragma unroll
        for (int m = 0; m < MF; ++m) {
            int row = row0 + wm * MF * 16 + m * 16 + q * 4;
#pragma unroll
            for (int r = 0; r < 4; ++r) {
                float v = acc[m][n][r] + bv;
                if (ACT == 1) v = fmaxf(v, 0.f);
                if (ACT == 2) v = 1.0f / (1.0f + __expf(-v));
                if (OUT_BF16)
                    ((unsigned short*)C)[(size_t)(row + r) * ldc + col] = f2bf(v);
                else
                    __builtin_nontemporal_store(
                        v, &((float*)C)[(size_t)(row + r) * ldc + col]);
            }
        }
    }
}

// ---------------------------------------------------------------------------
// mlp_mid v2 + W4-transpose piggyback.
// Blocks [0,256): h2 = relu((h1@W2 + b2) @ W3 + b3), 16 rows/block, split-K.
// Blocks [256,360): W4 [512][784] -> W4B [832][512] transpose (for GEMM4).
// ---------------------------------------------------------------------------
__global__ __launch_bounds__(256)
void mlp_mid(const unsigned short* __restrict__ h1B,   // [4096][512]
             const unsigned short* __restrict__ W2T,   // [32][512]
             const unsigned short* __restrict__ W3T,   // [512][32]
             const float* __restrict__ b2,             // [32]
             const float* __restrict__ b3,             // [512]
             const float* __restrict__ W4,             // [512][784]
             unsigned short* __restrict__ h2B,         // [4096][512]
             unsigned short* __restrict__ W4B) {       // [832][512]
    __shared__ float shm[64 * 65];          // 16.6 KB (both roles)

    const int t  = threadIdx.x;

    if (blockIdx.x >= 256) {
        // -- W4 transpose: 104 blocks (8 kt x 13 nt), pad rows zeroed --
        float (*T)[65] = (float (*)[65])shm;
        int bb = blockIdx.x - 256;
        int k0 = (bb / 13) * 64, n0 = (bb % 13) * 64;
        int rr = t >> 6, c = t & 63;
#pragma unroll
        for (int i = 0; i < 16; ++i) {
            int r = i * 4 + rr;
            T[r][c] = (n0 + c < FEATDIM) ? W4[(size_t)(k0 + r) * FEATDIM + n0 + c] : 0.f;
        }
        __syncthreads();
#pragma unroll
        for (int i = 0; i < 16; ++i) {
            int nn = i * 4 + rr;
            W4B[(size_t)(n0 + nn) * 512 + k0 + c] = f2bf(T[c][nn]);
        }
        return;
    }

    float (*part)[34] = (float (*)[34])shm;     // [64][34] padded
    const int w  = t >> 6;
    const int l  = t & 63;
    const int q  = l >> 4;
    const int lx = l & 15;
    const int row0 = blockIdx.x * 16;

    // ---- phase A: partial lat over this wave's K-chunk ----
    f4 acc0 = (f4)0.f, acc1 = (f4)0.f;
#pragma unroll
    for (int s = 0; s < 4; ++s) {
        const int k0 = w * 128 + s * 32 + q * 8;
        b8 a   = *(const b8*)&h1B[(size_t)(row0 + lx) * 512 + k0];
        b8 bf0 = *(const b8*)&W2T[(size_t)lx * 512 + k0];
        b8 bf1 = *(const b8*)&W2T[(size_t)(16 + lx) * 512 + k0];
        acc0 = __builtin_amdgcn_mfma_f32_16x16x32_bf16(a, bf0, acc0, 0, 0, 0);
        acc1 = __builtin_amdgcn_mfma_f32_16x16x32_bf16(a, bf1, acc1, 0, 0, 0);
    }
#pragma unroll
    for (int r = 0; r < 4; ++r) {
        part[w * 16 + q * 4 + r][lx]      = acc0[r];
        part[w * 16 + q * 4 + r][16 + lx] = acc1[r];
    }
    __syncthreads();

    // ---- reduce partials -> lat A-fragment (row=lx, k=q*8..+8) ----
    union { unsigned short us[8]; b8 v; } au;
#pragma unroll
    for (int j = 0; j < 8; ++j) {
        const int c = q * 8 + j;
        float s = b2[c];
#pragma unroll
        for (int ww = 0; ww < 4; ++ww) s += part[ww * 16 + lx][c];
        au.us[j] = f2bf(s);
    }
    const b8 a2 = au.v;

    // ---- phase B: h2 rows row0..+16, cols w*128..+128 ----
#pragma unroll
    for (int jg = 0; jg < 8; ++jg) {
        const int col = (w * 8 + jg) * 16 + lx;
        b8 bf = *(const b8*)&W3T[(size_t)col * 32 + q * 8];
        f4 o = __builtin_amdgcn_mfma_f32_16x16x32_bf16(a2, bf, (f4)0.f, 0, 0, 0);
        const float bb = b3[col];
#pragma unroll
        for (int r = 0; r < 4; ++r) {
            float v = fmaxf(o[r] + bb, 0.f);
            h2B[(size_t)(row0 + q * 4 + r) * 512 + col] = f2bf(v);
        }
    }
}

// ---------------------------------------------------------------------------
extern "C" void kernel_launch(void* const* d_in, const int* in_sizes, int n_in,
                              void* d_out, int out_size, void* d_ws, size_t ws_size,
                              hipStream_t stream) {
    const float* x     = (const float*)d_in[0];
    const float* theta = (const float*)d_in[1];
    const float* W1    = (const float*)d_in[2];
    const float* b1    = (const float*)d_in[3];
    const float* W2    = (const float*)d_in[4];
    const float* b2    = (const float*)d_in[5];
    const float* W3    = (const float*)d_in[6];
    const float* b3    = (const float*)d_in[7];
    const float* W4    = (const float*)d_in[8];
    const float* b4    = (const float*)d_in[9];
    float* out = (float*)d_out;

    // workspace layout
    char* ws = (char*)d_ws;
    unsigned short* featsB = (unsigned short*)ws;   ws += (size_t)BATCH * KP1 * 2;
    unsigned short* W1B    = (unsigned short*)ws;   ws += (size_t)512 * KP1 * 2;
    unsigned short* W4B    = (unsigned short*)ws;   ws += (size_t)NP4 * 512 * 2;
    unsigned short* W2T    = (unsigned short*)ws;   ws += (size_t)32 * 512 * 2;
    unsigned short* W3T    = (unsigned short*)ws;   ws += (size_t)512 * 32 * 2;
    unsigned short* h1B    = (unsigned short*)ws;   ws += (size_t)BATCH * 512 * 2;
    unsigned short* h2B    = (unsigned short*)ws;

    prep_kernel<<<W3T_END, 256, 0, stream>>>(
        x, theta, W1, W2, W3, featsB, W1B, W2T, W3T);

    // GEMM1: feats[4096,832] @ W1 -> h1 (relu, bf16); 8-wave, BK=128+half tail
    gemm_mfma<8, 1, 2, 1, 1><<<512, 512, 0, stream>>>(
        featsB, W1B, b1, h1B, KP1, KP1, 512, 512, 7, 1, 8);
    // mlp_mid: h1 -> h2 (split-K thin pair) + W4 transpose; grid 256+104
    mlp_mid<<<360, 256, 0, stream>>>(h1B, W2T, W3T, b2, b3, W4, h2B, W4B);
    // GEMM4: h2[4096,512] @ W4 -> out (sigmoid, fp32); 8-wave, BK=64
    gemm_mfma<8, 1, 1, 2, 0><<<832, 512, 0, stream>>>(
        h2B, W4B, b4, out, 512, 512, FEATDIM, FEATDIM, 8, 0, 13);
}

// Round 18
// 45.731 us; speedup vs baseline: 1.0199x; 1.0199x over previous
//
#include <hip/hip_runtime.h>
#include <hip/hip_bf16.h>
#include <math.h>

// ---------------------------------------------------------------------------
// QuanvolutionAutoencoder, B=4096, fp32 in/out.
//   feats = quanv(x, theta)              [4096,784]
//   h1    = relu(feats @ W1 + b1)        [4096,512]
//   lat   = h1 @ W2 + b2                 [4096,32]    } fused row-local
//   h2    = relu(lat @ W3 + b3)          [4096,512]   } (mlp_mid kernel)
//   out   = sigmoid(h2 @ W4 + b4)        [4096,784]
// 4 dispatches: prep (quanv 2 patches/thread, in-register gates, HW trig),
// GEMM1 (8-wave 64x64 BK=128), mlp_mid (+W4 transpose), GEMM4 (8-wave BK=64).
// ---------------------------------------------------------------------------

#define BATCH   4096
#define NPATCH  196
#define FEATDIM 784
#define KP1     832     // K for GEMM1 padded to 13*64 (final 64 via half step)
#define NP4     832     // N for GEMM4 padded to 13*64

typedef __bf16 b8 __attribute__((ext_vector_type(8)));
typedef float  f4 __attribute__((ext_vector_type(4)));

__device__ __forceinline__ unsigned short f2bf(float f) {
    unsigned u = __float_as_uint(f);
    u += 0x7FFF + ((u >> 16) & 1);          // round-to-nearest-even
    return (unsigned short)(u >> 16);
}

__device__ __forceinline__ void gload16(const void* g, void* l) {
    __builtin_amdgcn_global_load_lds(
        (const __attribute__((address_space(1))) unsigned int*)g,
        (__attribute__((address_space(3))) unsigned int*)l, 16, 0, 0);
}

// sin(x/2), cos(x/2) via hardware v_sin_f32/v_cos_f32 (D = sin(S0*2pi)).
// rev = x * 1/(4pi); all inputs here give rev in [0, 0.5) -> no reduction.
#define REV4PI 0.07957747154594767f
__device__ __forceinline__ float hsin2(float x) {
    return __builtin_amdgcn_sinf(x * REV4PI);
}
__device__ __forceinline__ float hcos2(float x) {
    return __builtin_amdgcn_cosf(x * REV4PI);
}

// ---------------------------------------------------------------------------
// Prep kernel block roles:
//   [0, 1568)        quanv -> featsB (bf16, pitch 832); 2 patches/thread,
//                    p<6 threads also zero the row's pad cols
//   [1568, 1672)     W1 transpose (LDS-tiled): W1B[n*832+k], pads zeroed
//   [1672, 1736)     W2T[n*512+k] = bf16(W2[k*32+n])       (32x512)
//   [1736, 1800)     W3T[n*32+k]  = bf16(W3[k*512+n])      (512x32)
// (W4 transpose piggybacks on mlp_mid.)
// ---------------------------------------------------------------------------
#define Q_END   1568
#define T1_END  1672
#define W2T_END 1736
#define W3T_END 1800

__global__ __launch_bounds__(256)
void prep_kernel(const float* __restrict__ x, const float* __restrict__ theta,
                 const float* __restrict__ W1, const float* __restrict__ W2,
                 const float* __restrict__ W3,
                 unsigned short* __restrict__ featsB,
                 unsigned short* __restrict__ W1B,
                 unsigned short* __restrict__ W2T,
                 unsigned short* __restrict__ W3T) {
    __shared__ float shm[64 * 65];          // 16.6 KB; used by transpose role
    const int bid = blockIdx.x;
    const int tid = threadIdx.x;

    if (bid < Q_END) {
        // ---- quanvolution: 2 patches/thread, in-register gate application ----
        // gate angles (wave-uniform): PAIRS bit=3-wire
        float ct[8], st[8];
#pragma unroll
        for (int k = 0; k < 8; ++k) {
            float th = theta[k];
            ct[k] = hcos2(th);
            st[k] = hsin2(th);
        }
        const int cb[8] = {3, 2, 1, 0, 3, 2, 1, 0};
        const int tb[8] = {2, 1, 0, 3, 1, 0, 3, 2};

#pragma unroll 1
        for (int u = 0; u < 2; ++u) {
            int n = (bid * 2 + u) * 256 + tid;
            int b = n / NPATCH;
            int p = n % NPATCH;
            int r = p / 14;
            int c = p % 14;

            const float* img = x + (size_t)b * FEATDIM;
            float2 p0 = *(const float2*)&img[(2 * r) * 28 + 2 * c];
            float2 p1 = *(const float2*)&img[(2 * r + 1) * 28 + 2 * c];

            float a0c = hcos2(p0.x), a0s = hsin2(p0.x);
            float a1c = hcos2(p0.y), a1s = hsin2(p0.y);
            float a2c = hcos2(p1.x), a2s = hsin2(p1.x);
            float a3c = hcos2(p1.y), a3s = hsin2(p1.y);

            // product state |psi> via 4->8->16 tree (wire w -> bit 3-w)
            float w01[4], w012[8], stv[16];
            w01[0] = a0c * a1c; w01[1] = a0c * a1s;
            w01[2] = a0s * a1c; w01[3] = a0s * a1s;
#pragma unroll
            for (int i = 0; i < 4; ++i) {
                w012[2 * i]     = w01[i] * a2c;
                w012[2 * i + 1] = w01[i] * a2s;
            }
#pragma unroll
            for (int i = 0; i < 8; ++i) {
                stv[2 * i]     = w012[i] * a3c;
                stv[2 * i + 1] = w012[i] * a3s;
            }

#pragma unroll
            for (int k = 0; k < 8; ++k) {
                const int cm = 1 << cb[k], tm = 1 << tb[k];
#pragma unroll
                for (int s = 0; s < 16; ++s) {
                    if ((s & cm) && !(s & tm)) {    // compile-time after unroll
                        float v0 = stv[s], v1 = stv[s | tm];
                        stv[s]      = ct[k] * v0 - st[k] * v1;
                        stv[s | tm] = st[k] * v0 + ct[k] * v1;
                    }
                }
            }

            float m0 = 0.f, m1 = 0.f, m2 = 0.f, m3 = 0.f;
#pragma unroll
            for (int s = 0; s < 16; ++s) {
                float pr = stv[s] * stv[s];
                m0 += (s & 8) ? -pr : pr;
                m1 += (s & 4) ? -pr : pr;
                m2 += (s & 2) ? -pr : pr;
                m3 += (s & 1) ? -pr : pr;
            }
            ushort4 o;
            o.x = f2bf(m0); o.y = f2bf(m1); o.z = f2bf(m2); o.w = f2bf(m3);
            *(ushort4*)&featsB[(size_t)b * KP1 + p * 4] = o;
            // fold pad-zeroing: cols 784..831 of row b (6 float4), by p<6
            if (p < 6)
                *(float4*)&featsB[(size_t)b * KP1 + FEATDIM + p * 8] =
                    make_float4(0.f, 0.f, 0.f, 0.f);
        }
    } else if (bid < T1_END) {
        // -- W1 [784][512] -> W1B [512][832] (transpose, pads zeroed) --
        float (*T)[65] = (float (*)[65])shm;
        int bb = bid - Q_END;               // 13 kt x 8 nt
        int k0 = (bb / 8) * 64, n0 = (bb % 8) * 64;
        int rr = tid >> 6, c = tid & 63;
#pragma unroll
        for (int i = 0; i < 16; ++i) {
            int r = i * 4 + rr;
            if (k0 + r < FEATDIM) T[r][c] = W1[(size_t)(k0 + r) * 512 + n0 + c];
        }
        __syncthreads();
#pragma unroll
        for (int i = 0; i < 16; ++i) {
            int nn = i * 4 + rr;
            unsigned short v = (k0 + c < FEATDIM) ? f2bf(T[c][nn]) : (unsigned short)0;
            W1B[(size_t)(n0 + nn) * KP1 + k0 + c] = v;
        }
    } else if (bid < W2T_END) {
        // -- W2T[n*512+k] = bf16(W2[k*32+n]), n<32, k<512 --
        int idx = (bid - T1_END) * 256 + tid;   // 16384
        int n = idx >> 9, k = idx & 511;
        W2T[idx] = f2bf(W2[(size_t)k * 32 + n]);
    } else {
        // -- W3T[n*32+k] = bf16(W3[k*512+n]), n<512, k<32 --
        int idx = (bid - W2T_END) * 256 + tid;  // 16384
        int n = idx >> 5, k = idx & 31;
        W3T[idx] = f2bf(W3[(size_t)k * 512 + n]);
    }
}

// ---------------------------------------------------------------------------
// bf16 MFMA GEMM, tile 64x64, NW waves (NW*64 threads), BK = NH*64.
//   NW=4: waves 2M x 2N, 32x32/wave (MF=2).
//   NW=8: waves 4M x 2N, 16x32/wave (MF=1) -- 2x waves/SIMD (R14-proven).
// dbuf LDS, gload16 with XOR-swizzled source, XCD-chunked blockIdx.
// khalf: final K-step half (NH=2 only). ACT: 1=relu, 2=sigmoid.
// OUT_BF16: 1 bf16 / 0 fp32 (nt store).
// ---------------------------------------------------------------------------
template <int NW, int MF, int NH, int ACT, int OUT_BF16>
__global__ __launch_bounds__(NW * 64)
void gemm_mfma(const unsigned short* __restrict__ A,   // [M][lda] bf16
               const unsigned short* __restrict__ BT,  // [Npad][ldb] bf16
               const float* __restrict__ bias,         // [Nlog] fp32
               void* __restrict__ C,                   // [M][ldc]
               int lda, int ldb, int ldc, int Nlog, int nkt, int khalf,
               int gx) {
    __shared__ __align__(16) unsigned short As[2][NH][64 * 64];
    __shared__ __align__(16) unsigned short Bs[2][NH][64 * 64];

    const int nwg = gridDim.x;
    const int d   = blockIdx.x;
    const int tile = (d & 7) * (nwg >> 3) + (d >> 3);
    const int bx = tile % gx;
    const int by = tile / gx;

    const int t  = threadIdx.x;
    const int w  = t >> 6;
    const int l  = t & 63;
    const int wm = w >> 1;                  // M index (0..NW/2-1)
    const int wn = w & 1;                   // N half
    const int row0 = by * 64;
    const int col0 = bx * 64;

    const int sr = l >> 3;
    const int sc = ((l & 7) ^ sr) * 8;
    const unsigned short* Ab = A  + (size_t)(row0 + w * 8 + sr) * lda + sc;
    const unsigned short* Bb = BT + (size_t)(col0 + w * 8 + sr) * ldb + sc;

    const int q  = l >> 4;
    const int lx = l & 15;
    const int sx = l & 7;
    const int coff[2] = { ((0 + q) ^ sx) * 16, ((4 + q) ^ sx) * 16 };

    f4 acc[MF][2];
#pragma unroll
    for (int m = 0; m < MF; ++m)
#pragma unroll
        for (int n = 0; n < 2; ++n) acc[m][n] = (f4)0.f;

    constexpr int ITS = 64 / (NW * 8);      // staging passes over 64 rows

    auto stage = [&](int bi, int kt) {
        const int nh = (NH == 2 && khalf && kt == nkt - 1) ? 1 : NH;
        for (int h = 0; h < nh; ++h) {
            const size_t k0 = (size_t)kt * (NH * 64) + h * 64;
            char* la = (char*)&As[bi][h][0] + w * 1024;
            char* lb = (char*)&Bs[bi][h][0] + w * 1024;
#pragma unroll
            for (int it = 0; it < ITS; ++it) {
                gload16(Ab + (size_t)(it * NW * 8) * lda + k0, la + it * NW * 1024);
                gload16(Bb + (size_t)(it * NW * 8) * ldb + k0, lb + it * NW * 1024);
            }
        }
    };

    auto compute = [&](int bi, int kt) {
        const int nh = (NH == 2 && khalf && kt == nkt - 1) ? 1 : NH;
        for (int h = 0; h < nh; ++h) {
            const char* la = (const char*)&As[bi][h][0];
            const char* lb = (const char*)&Bs[bi][h][0];
#pragma unroll
            for (int kk = 0; kk < 2; ++kk) {
                const int co = coff[kk];
                b8 a[MF], bf[2];
#pragma unroll
                for (int m = 0; m < MF; ++m)
                    a[m] = *(const b8*)(la + (wm * MF * 16 + m * 16 + lx) * 128 + co);
#pragma unroll
                for (int n = 0; n < 2; ++n)
                    bf[n] = *(const b8*)(lb + (wn * 32 + n * 16 + lx) * 128 + co);
#pragma unroll
                for (int m = 0; m < MF; ++m)
#pragma unroll
                    for (int n = 0; n < 2; ++n)
                        acc[m][n] = __builtin_amdgcn_mfma_f32_16x16x32_bf16(
                            a[m], bf[n], acc[m][n], 0, 0, 0);
            }
        }
    };

    stage(0, 0);
    __syncthreads();
    for (int kt = 0; kt < nkt; ++kt) {
        if (kt + 1 < nkt) stage((kt + 1) & 1, kt + 1);
        compute(kt & 1, kt);
        __syncthreads();
    }

#pragma unroll
    for (int n = 0; n < 2; ++n) {
        int col = col0 + wn * 32 + n * 16 + lx;
        if (col >= Nlog) continue;
        float bv = bias[col];
#pragma unroll
        for (int m = 0; m < MF; ++m) {
            int row = row0 + wm * MF * 16 + m * 16 + q * 4;
#pragma unroll
            for (int r = 0; r < 4; ++r) {
                float v = acc[m][n][r] + bv;
                if (ACT == 1) v = fmaxf(v, 0.f);
                if (ACT == 2) v = 1.0f / (1.0f + __expf(-v));
                if (OUT_BF16)
                    ((unsigned short*)C)[(size_t)(row + r) * ldc + col] = f2bf(v);
                else
                    __builtin_nontemporal_store(
                        v, &((float*)C)[(size_t)(row + r) * ldc + col]);
            }
        }
    }
}

// ---------------------------------------------------------------------------
// mlp_mid v2 + W4-transpose piggyback.
// Blocks [0,256): h2 = relu((h1@W2 + b2) @ W3 + b3), 16 rows/block, split-K.
// Blocks [256,360): W4 [512][784] -> W4B [832][512] transpose (for GEMM4).
// ---------------------------------------------------------------------------
__global__ __launch_bounds__(256)
void mlp_mid(const unsigned short* __restrict__ h1B,   // [4096][512]
             const unsigned short* __restrict__ W2T,   // [32][512]
             const unsigned short* __restrict__ W3T,   // [512][32]
             const float* __restrict__ b2,             // [32]
             const float* __restrict__ b3,             // [512]
             const float* __restrict__ W4,             // [512][784]
             unsigned short* __restrict__ h2B,         // [4096][512]
             unsigned short* __restrict__ W4B) {       // [832][512]
    __shared__ float shm[64 * 65];          // 16.6 KB (both roles)

    const int t  = threadIdx.x;

    if (blockIdx.x >= 256) {
        // -- W4 transpose: 104 blocks (8 kt x 13 nt), pad rows zeroed --
        float (*T)[65] = (float (*)[65])shm;
        int bb = blockIdx.x - 256;
        int k0 = (bb / 13) * 64, n0 = (bb % 13) * 64;
        int rr = t >> 6, c = t & 63;
#pragma unroll
        for (int i = 0; i < 16; ++i) {
            int r = i * 4 + rr;
            T[r][c] = (n0 + c < FEATDIM) ? W4[(size_t)(k0 + r) * FEATDIM + n0 + c] : 0.f;
        }
        __syncthreads();
#pragma unroll
        for (int i = 0; i < 16; ++i) {
            int nn = i * 4 + rr;
            W4B[(size_t)(n0 + nn) * 512 + k0 + c] = f2bf(T[c][nn]);
        }
        return;
    }

    float (*part)[34] = (float (*)[34])shm;     // [64][34] padded
    const int w  = t >> 6;
    const int l  = t & 63;
    const int q  = l >> 4;
    const int lx = l & 15;
    const int row0 = blockIdx.x * 16;

    // ---- phase A: partial lat over this wave's K-chunk ----
    f4 acc0 = (f4)0.f, acc1 = (f4)0.f;
#pragma unroll
    for (int s = 0; s < 4; ++s) {
        const int k0 = w * 128 + s * 32 + q * 8;
        b8 a   = *(const b8*)&h1B[(size_t)(row0 + lx) * 512 + k0];
        b8 bf0 = *(const b8*)&W2T[(size_t)lx * 512 + k0];
        b8 bf1 = *(const b8*)&W2T[(size_t)(16 + lx) * 512 + k0];
        acc0 = __builtin_amdgcn_mfma_f32_16x16x32_bf16(a, bf0, acc0, 0, 0, 0);
        acc1 = __builtin_amdgcn_mfma_f32_16x16x32_bf16(a, bf1, acc1, 0, 0, 0);
    }
#pragma unroll
    for (int r = 0; r < 4; ++r) {
        part[w * 16 + q * 4 + r][lx]      = acc0[r];
        part[w * 16 + q * 4 + r][16 + lx] = acc1[r];
    }
    __syncthreads();

    // ---- reduce partials -> lat A-fragment (row=lx, k=q*8..+8) ----
    union { unsigned short us[8]; b8 v; } au;
#pragma unroll
    for (int j = 0; j < 8; ++j) {
        const int c = q * 8 + j;
        float s = b2[c];
#pragma unroll
        for (int ww = 0; ww < 4; ++ww) s += part[ww * 16 + lx][c];
        au.us[j] = f2bf(s);
    }
    const b8 a2 = au.v;

    // ---- phase B: h2 rows row0..+16, cols w*128..+128 ----
#pragma unroll
    for (int jg = 0; jg < 8; ++jg) {
        const int col = (w * 8 + jg) * 16 + lx;
        b8 bf = *(const b8*)&W3T[(size_t)col * 32 + q * 8];
        f4 o = __builtin_amdgcn_mfma_f32_16x16x32_bf16(a2, bf, (f4)0.f, 0, 0, 0);
        const float bb = b3[col];
#pragma unroll
        for (int r = 0; r < 4; ++r) {
            float v = fmaxf(o[r] + bb, 0.f);
            h2B[(size_t)(row0 + q * 4 + r) * 512 + col] = f2bf(v);
        }
    }
}

// ---------------------------------------------------------------------------
extern "C" void kernel_launch(void* const* d_in, const int* in_sizes, int n_in,
                              void* d_out, int out_size, void* d_ws, size_t ws_size,
                              hipStream_t stream) {
    const float* x     = (const float*)d_in[0];
    const float* theta = (const float*)d_in[1];
    const float* W1    = (const float*)d_in[2];
    const float* b1    = (const float*)d_in[3];
    const float* W2    = (const float*)d_in[4];
    const float* b2    = (const float*)d_in[5];
    const float* W3    = (const float*)d_in[6];
    const float* b3    = (const float*)d_in[7];
    const float* W4    = (const float*)d_in[8];
    const float* b4    = (const float*)d_in[9];
    float* out = (float*)d_out;

    // workspace layout
    char* ws = (char*)d_ws;
    unsigned short* featsB = (unsigned short*)ws;   ws += (size_t)BATCH * KP1 * 2;
    unsigned short* W1B    = (unsigned short*)ws;   ws += (size_t)512 * KP1 * 2;
    unsigned short* W4B    = (unsigned short*)ws;   ws += (size_t)NP4 * 512 * 2;
    unsigned short* W2T    = (unsigned short*)ws;   ws += (size_t)32 * 512 * 2;
    unsigned short* W3T    = (unsigned short*)ws;   ws += (size_t)512 * 32 * 2;
    unsigned short* h1B    = (unsigned short*)ws;   ws += (size_t)BATCH * 512 * 2;
    unsigned short* h2B    = (unsigned short*)ws;

    prep_kernel<<<W3T_END, 256, 0, stream>>>(
        x, theta, W1, W2, W3, featsB, W1B, W2T, W3T);

    // GEMM1: feats[4096,832] @ W1 -> h1 (relu, bf16); 8-wave, BK=128+half tail
    gemm_mfma<8, 1, 2, 1, 1><<<512, 512, 0, stream>>>(
        featsB, W1B, b1, h1B, KP1, KP1, 512, 512, 7, 1, 8);
    // mlp_mid: h1 -> h2 (split-K thin pair) + W4 transpose; grid 256+104
    mlp_mid<<<360, 256, 0, stream>>>(h1B, W2T, W3T, b2, b3, W4, h2B, W4B);
    // GEMM4: h2[4096,512] @ W4 -> out (sigmoid, fp32); 8-wave, BK=64
    gemm_mfma<8, 1, 1, 2, 0><<<832, 512, 0, stream>>>(
        h2B, W4B, b4, out, 512, 512, FEATDIM, FEATDIM, 8, 0, 13);
}

// Round 19
// 44.878 us; speedup vs baseline: 1.0393x; 1.0190x over previous
//
#include <hip/hip_runtime.h>
#include <hip/hip_bf16.h>
#include <math.h>

// ---------------------------------------------------------------------------
// QuanvolutionAutoencoder, B=4096, fp32 in/out.
//   feats = quanv(x, theta)              [4096,784]
//   h1    = relu(feats @ W1 + b1)        [4096,512]
//   lat   = h1 @ W2 + b2                 [4096,32]    } fused row-local
//   h2    = relu(lat @ W3 + b3)          [4096,512]   } (mlp_mid kernel)
//   out   = sigmoid(h2 @ W4 + b4)        [4096,784]
// 4 dispatches: prep (transposes first, quanv 4 patches/thread), GEMM1
// (8-wave 64x64 BK=128), mlp_mid (+W4 transpose), GEMM4 (8-wave BK=64).
// ---------------------------------------------------------------------------

#define BATCH   4096
#define NPATCH  196
#define FEATDIM 784
#define KP1     832     // K for GEMM1 padded to 13*64 (final 64 via half step)
#define NP4     832     // N for GEMM4 padded to 13*64

typedef __bf16 b8 __attribute__((ext_vector_type(8)));
typedef float  f4 __attribute__((ext_vector_type(4)));

__device__ __forceinline__ unsigned short f2bf(float f) {
    unsigned u = __float_as_uint(f);
    u += 0x7FFF + ((u >> 16) & 1);          // round-to-nearest-even
    return (unsigned short)(u >> 16);
}

__device__ __forceinline__ void gload16(const void* g, void* l) {
    __builtin_amdgcn_global_load_lds(
        (const __attribute__((address_space(1))) unsigned int*)g,
        (__attribute__((address_space(3))) unsigned int*)l, 16, 0, 0);
}

// sin(x/2), cos(x/2) via hardware v_sin_f32/v_cos_f32 (D = sin(S0*2pi)).
// rev = x * 1/(4pi); all inputs here give rev in [0, 0.5) -> no reduction.
#define REV4PI 0.07957747154594767f
__device__ __forceinline__ float hsin2(float x) {
    return __builtin_amdgcn_sinf(x * REV4PI);
}
__device__ __forceinline__ float hcos2(float x) {
    return __builtin_amdgcn_cosf(x * REV4PI);
}

// ---------------------------------------------------------------------------
// Prep kernel block roles (weight prep FIRST so it overlaps the quanv bulk):
//   [0, 104)         W1 transpose (LDS-tiled): W1B[n*832+k], pads zeroed
//   [104, 168)       W2T[n*512+k] = bf16(W2[k*32+n])       (32x512)
//   [168, 232)       W3T[n*32+k]  = bf16(W3[k*512+n])      (512x32)
//   [232, 1016)      quanv -> featsB (bf16, pitch 832); 4 patches/thread,
//                    p<6 threads also zero the row's pad cols
// (W4 transpose piggybacks on mlp_mid.)
// ---------------------------------------------------------------------------
#define T1_END  104
#define W2T_END 168
#define W3T_END 232
#define Q_END   1016

__global__ __launch_bounds__(256)
void prep_kernel(const float* __restrict__ x, const float* __restrict__ theta,
                 const float* __restrict__ W1, const float* __restrict__ W2,
                 const float* __restrict__ W3,
                 unsigned short* __restrict__ featsB,
                 unsigned short* __restrict__ W1B,
                 unsigned short* __restrict__ W2T,
                 unsigned short* __restrict__ W3T) {
    __shared__ float shm[64 * 65];          // 16.6 KB; used by transpose role
    const int bid = blockIdx.x;
    const int tid = threadIdx.x;

    if (bid >= W3T_END) {
        // ---- quanvolution: 4 patches/thread, in-register gate application ----
        // gate angles (wave-uniform): PAIRS bit=3-wire
        float ct[8], st[8];
#pragma unroll
        for (int k = 0; k < 8; ++k) {
            float th = theta[k];
            ct[k] = hcos2(th);
            st[k] = hsin2(th);
        }
        const int cb[8] = {3, 2, 1, 0, 3, 2, 1, 0};
        const int tb[8] = {2, 1, 0, 3, 1, 0, 3, 2};
        const int qb = bid - W3T_END;       // 0..783

#pragma unroll 1
        for (int u = 0; u < 4; ++u) {
            int n = (qb * 4 + u) * 256 + tid;
            int b = n / NPATCH;
            int p = n % NPATCH;
            int r = p / 14;
            int c = p % 14;

            const float* img = x + (size_t)b * FEATDIM;
            float2 p0 = *(const float2*)&img[(2 * r) * 28 + 2 * c];
            float2 p1 = *(const float2*)&img[(2 * r + 1) * 28 + 2 * c];

            float a0c = hcos2(p0.x), a0s = hsin2(p0.x);
            float a1c = hcos2(p0.y), a1s = hsin2(p0.y);
            float a2c = hcos2(p1.x), a2s = hsin2(p1.x);
            float a3c = hcos2(p1.y), a3s = hsin2(p1.y);

            // product state |psi> via 4->8->16 tree (wire w -> bit 3-w)
            float w01[4], w012[8], stv[16];
            w01[0] = a0c * a1c; w01[1] = a0c * a1s;
            w01[2] = a0s * a1c; w01[3] = a0s * a1s;
#pragma unroll
            for (int i = 0; i < 4; ++i) {
                w012[2 * i]     = w01[i] * a2c;
                w012[2 * i + 1] = w01[i] * a2s;
            }
#pragma unroll
            for (int i = 0; i < 8; ++i) {
                stv[2 * i]     = w012[i] * a3c;
                stv[2 * i + 1] = w012[i] * a3s;
            }

#pragma unroll
            for (int k = 0; k < 8; ++k) {
                const int cm = 1 << cb[k], tm = 1 << tb[k];
#pragma unroll
                for (int s = 0; s < 16; ++s) {
                    if ((s & cm) && !(s & tm)) {    // compile-time after unroll
                        float v0 = stv[s], v1 = stv[s | tm];
                        stv[s]      = ct[k] * v0 - st[k] * v1;
                        stv[s | tm] = st[k] * v0 + ct[k] * v1;
                    }
                }
            }

            float m0 = 0.f, m1 = 0.f, m2 = 0.f, m3 = 0.f;
#pragma unroll
            for (int s = 0; s < 16; ++s) {
                float pr = stv[s] * stv[s];
                m0 += (s & 8) ? -pr : pr;
                m1 += (s & 4) ? -pr : pr;
                m2 += (s & 2) ? -pr : pr;
                m3 += (s & 1) ? -pr : pr;
            }
            ushort4 o;
            o.x = f2bf(m0); o.y = f2bf(m1); o.z = f2bf(m2); o.w = f2bf(m3);
            *(ushort4*)&featsB[(size_t)b * KP1 + p * 4] = o;
            // fold pad-zeroing: cols 784..831 of row b (6 float4), by p<6
            if (p < 6)
                *(float4*)&featsB[(size_t)b * KP1 + FEATDIM + p * 8] =
                    make_float4(0.f, 0.f, 0.f, 0.f);
        }
    } else if (bid < T1_END) {
        // -- W1 [784][512] -> W1B [512][832] (transpose, pads zeroed) --
        float (*T)[65] = (float (*)[65])shm;
        int bb = bid;                       // 13 kt x 8 nt
        int k0 = (bb / 8) * 64, n0 = (bb % 8) * 64;
        int rr = tid >> 6, c = tid & 63;
#pragma unroll
        for (int i = 0; i < 16; ++i) {
            int r = i * 4 + rr;
            if (k0 + r < FEATDIM) T[r][c] = W1[(size_t)(k0 + r) * 512 + n0 + c];
        }
        __syncthreads();
#pragma unroll
        for (int i = 0; i < 16; ++i) {
            int nn = i * 4 + rr;
            unsigned short v = (k0 + c < FEATDIM) ? f2bf(T[c][nn]) : (unsigned short)0;
            W1B[(size_t)(n0 + nn) * KP1 + k0 + c] = v;
        }
    } else if (bid < W2T_END) {
        // -- W2T[n*512+k] = bf16(W2[k*32+n]), n<32, k<512 --
        int idx = (bid - T1_END) * 256 + tid;   // 16384
        int n = idx >> 9, k = idx & 511;
        W2T[idx] = f2bf(W2[(size_t)k * 32 + n]);
    } else {
        // -- W3T[n*32+k] = bf16(W3[k*512+n]), n<512, k<32 --
        int idx = (bid - W2T_END) * 256 + tid;  // 16384
        int n = idx >> 5, k = idx & 31;
        W3T[idx] = f2bf(W3[(size_t)k * 512 + n]);
    }
}

// ---------------------------------------------------------------------------
// bf16 MFMA GEMM, tile 64x64, NW waves (NW*64 threads), BK = NH*64.
//   NW=4: waves 2M x 2N, 32x32/wave (MF=2).
//   NW=8: waves 4M x 2N, 16x32/wave (MF=1) -- 2x waves/SIMD (R14-proven).
// dbuf LDS, gload16 with XOR-swizzled source, XCD-chunked blockIdx.
// khalf: final K-step half (NH=2 only). ACT: 1=relu, 2=sigmoid.
// OUT_BF16: 1 bf16 / 0 fp32 (nt store).
// ---------------------------------------------------------------------------
template <int NW, int MF, int NH, int ACT, int OUT_BF16>
__global__ __launch_bounds__(NW * 64)
void gemm_mfma(const unsigned short* __restrict__ A,   // [M][lda] bf16
               const unsigned short* __restrict__ BT,  // [Npad][ldb] bf16
               const float* __restrict__ bias,         // [Nlog] fp32
               void* __restrict__ C,                   // [M][ldc]
               int lda, int ldb, int ldc, int Nlog, int nkt, int khalf,
               int gx) {
    __shared__ __align__(16) unsigned short As[2][NH][64 * 64];
    __shared__ __align__(16) unsigned short Bs[2][NH][64 * 64];

    const int nwg = gridDim.x;
    const int d   = blockIdx.x;
    const int tile = (d & 7) * (nwg >> 3) + (d >> 3);
    const int bx = tile % gx;
    const int by = tile / gx;

    const int t  = threadIdx.x;
    const int w  = t >> 6;
    const int l  = t & 63;
    const int wm = w >> 1;                  // M index (0..NW/2-1)
    const int wn = w & 1;                   // N half
    const int row0 = by * 64;
    const int col0 = bx * 64;

    const int sr = l >> 3;
    const int sc = ((l & 7) ^ sr) * 8;
    const unsigned short* Ab = A  + (size_t)(row0 + w * 8 + sr) * lda + sc;
    const unsigned short* Bb = BT + (size_t)(col0 + w * 8 + sr) * ldb + sc;

    const int q  = l >> 4;
    const int lx = l & 15;
    const int sx = l & 7;
    const int coff[2] = { ((0 + q) ^ sx) * 16, ((4 + q) ^ sx) * 16 };

    f4 acc[MF][2];
#pragma unroll
    for (int m = 0; m < MF; ++m)
#pragma unroll
        for (int n = 0; n < 2; ++n) acc[m][n] = (f4)0.f;

    constexpr int ITS = 64 / (NW * 8);      // staging passes over 64 rows

    auto stage = [&](int bi, int kt) {
        const int nh = (NH == 2 && khalf && kt == nkt - 1) ? 1 : NH;
        for (int h = 0; h < nh; ++h) {
            const size_t k0 = (size_t)kt * (NH * 64) + h * 64;
            char* la = (char*)&As[bi][h][0] + w * 1024;
            char* lb = (char*)&Bs[bi][h][0] + w * 1024;
#pragma unroll
            for (int it = 0; it < ITS; ++it) {
                gload16(Ab + (size_t)(it * NW * 8) * lda + k0, la + it * NW * 1024);
                gload16(Bb + (size_t)(it * NW * 8) * ldb + k0, lb + it * NW * 1024);
            }
        }
    };

    auto compute = [&](int bi, int kt) {
        const int nh = (NH == 2 && khalf && kt == nkt - 1) ? 1 : NH;
        for (int h = 0; h < nh; ++h) {
            const char* la = (const char*)&As[bi][h][0];
            const char* lb = (const char*)&Bs[bi][h][0];
#pragma unroll
            for (int kk = 0; kk < 2; ++kk) {
                const int co = coff[kk];
                b8 a[MF], bf[2];
#pragma unroll
                for (int m = 0; m < MF; ++m)
                    a[m] = *(const b8*)(la + (wm * MF * 16 + m * 16 + lx) * 128 + co);
#pragma unroll
                for (int n = 0; n < 2; ++n)
                    bf[n] = *(const b8*)(lb + (wn * 32 + n * 16 + lx) * 128 + co);
#pragma unroll
                for (int m = 0; m < MF; ++m)
#pragma unroll
                    for (int n = 0; n < 2; ++n)
                        acc[m][n] = __builtin_amdgcn_mfma_f32_16x16x32_bf16(
                            a[m], bf[n], acc[m][n], 0, 0, 0);
            }
        }
    };

    stage(0, 0);
    __syncthreads();
    for (int kt = 0; kt < nkt; ++kt) {
        if (kt + 1 < nkt) stage((kt + 1) & 1, kt + 1);
        compute(kt & 1, kt);
        __syncthreads();
    }

#pragma unroll
    for (int n = 0; n < 2; ++n) {
        int col = col0 + wn * 32 + n * 16 + lx;
        if (col >= Nlog) continue;
        float bv = bias[col];
#pragma unroll
        for (int m = 0; m < MF; ++m) {
            int row = row0 + wm * MF * 16 + m * 16 + q * 4;
#pragma unroll
            for (int r = 0; r < 4; ++r) {
                float v = acc[m][n][r] + bv;
                if (ACT == 1) v = fmaxf(v, 0.f);
                if (ACT == 2) v = 1.0f / (1.0f + __expf(-v));
                if (OUT_BF16)
                    ((unsigned short*)C)[(size_t)(row + r) * ldc + col] = f2bf(v);
                else
                    __builtin_nontemporal_store(
                        v, &((float*)C)[(size_t)(row + r) * ldc + col]);
            }
        }
    }
}

// ---------------------------------------------------------------------------
// mlp_mid v2 + W4-transpose piggyback.
// Blocks [0,256): h2 = relu((h1@W2 + b2) @ W3 + b3), 16 rows/block, split-K.
// Blocks [256,360): W4 [512][784] -> W4B [832][512] transpose (for GEMM4).
// ---------------------------------------------------------------------------
__global__ __launch_bounds__(256)
void mlp_mid(const unsigned short* __restrict__ h1B,   // [4096][512]
             const unsigned short* __restrict__ W2T,   // [32][512]
             const unsigned short* __restrict__ W3T,   // [512][32]
             const float* __restrict__ b2,             // [32]
             const float* __restrict__ b3,             // [512]
             const float* __restrict__ W4,             // [512][784]
             unsigned short* __restrict__ h2B,         // [4096][512]
             unsigned short* __restrict__ W4B) {       // [832][512]
    __shared__ float shm[64 * 65];          // 16.6 KB (both roles)

    const int t  = threadIdx.x;

    if (blockIdx.x >= 256) {
        // -- W4 transpose: 104 blocks (8 kt x 13 nt), pad rows zeroed --
        float (*T)[65] = (float (*)[65])shm;
        int bb = blockIdx.x - 256;
        int k0 = (bb / 13) * 64, n0 = (bb % 13) * 64;
        int rr = t >> 6, c = t & 63;
#pragma unroll
        for (int i = 0; i < 16; ++i) {
            int r = i * 4 + rr;
            T[r][c] = (n0 + c < FEATDIM) ? W4[(size_t)(k0 + r) * FEATDIM + n0 + c] : 0.f;
        }
        __syncthreads();
#pragma unroll
        for (int i = 0; i < 16; ++i) {
            int nn = i * 4 + rr;
            W4B[(size_t)(n0 + nn) * 512 + k0 + c] = f2bf(T[c][nn]);
        }
        return;
    }

    float (*part)[34] = (float (*)[34])shm;     // [64][34] padded
    const int w  = t >> 6;
    const int l  = t & 63;
    const int q  = l >> 4;
    const int lx = l & 15;
    const int row0 = blockIdx.x * 16;

    // ---- phase A: partial lat over this wave's K-chunk ----
    f4 acc0 = (f4)0.f, acc1 = (f4)0.f;
#pragma unroll
    for (int s = 0; s < 4; ++s) {
        const int k0 = w * 128 + s * 32 + q * 8;
        b8 a   = *(const b8*)&h1B[(size_t)(row0 + lx) * 512 + k0];
        b8 bf0 = *(const b8*)&W2T[(size_t)lx * 512 + k0];
        b8 bf1 = *(const b8*)&W2T[(size_t)(16 + lx) * 512 + k0];
        acc0 = __builtin_amdgcn_mfma_f32_16x16x32_bf16(a, bf0, acc0, 0, 0, 0);
        acc1 = __builtin_amdgcn_mfma_f32_16x16x32_bf16(a, bf1, acc1, 0, 0, 0);
    }
#pragma unroll
    for (int r = 0; r < 4; ++r) {
        part[w * 16 + q * 4 + r][lx]      = acc0[r];
        part[w * 16 + q * 4 + r][16 + lx] = acc1[r];
    }
    __syncthreads();

    // ---- reduce partials -> lat A-fragment (row=lx, k=q*8..+8) ----
    union { unsigned short us[8]; b8 v; } au;
#pragma unroll
    for (int j = 0; j < 8; ++j) {
        const int c = q * 8 + j;
        float s = b2[c];
#pragma unroll
        for (int ww = 0; ww < 4; ++ww) s += part[ww * 16 + lx][c];
        au.us[j] = f2bf(s);
    }
    const b8 a2 = au.v;

    // ---- phase B: h2 rows row0..+16, cols w*128..+128 ----
#pragma unroll
    for (int jg = 0; jg < 8; ++jg) {
        const int col = (w * 8 + jg) * 16 + lx;
        b8 bf = *(const b8*)&W3T[(size_t)col * 32 + q * 8];
        f4 o = __builtin_amdgcn_mfma_f32_16x16x32_bf16(a2, bf, (f4)0.f, 0, 0, 0);
        const float bb = b3[col];
#pragma unroll
        for (int r = 0; r < 4; ++r) {
            float v = fmaxf(o[r] + bb, 0.f);
            h2B[(size_t)(row0 + q * 4 + r) * 512 + col] = f2bf(v);
        }
    }
}

// ---------------------------------------------------------------------------
extern "C" void kernel_launch(void* const* d_in, const int* in_sizes, int n_in,
                              void* d_out, int out_size, void* d_ws, size_t ws_size,
                              hipStream_t stream) {
    const float* x     = (const float*)d_in[0];
    const float* theta = (const float*)d_in[1];
    const float* W1    = (const float*)d_in[2];
    const float* b1    = (const float*)d_in[3];
    const float* W2    = (const float*)d_in[4];
    const float* b2    = (const float*)d_in[5];
    const float* W3    = (const float*)d_in[6];
    const float* b3    = (const float*)d_in[7];
    const float* W4    = (const float*)d_in[8];
    const float* b4    = (const float*)d_in[9];
    float* out = (float*)d_out;

    // workspace layout
    char* ws = (char*)d_ws;
    unsigned short* featsB = (unsigned short*)ws;   ws += (size_t)BATCH * KP1 * 2;
    unsigned short* W1B    = (unsigned short*)ws;   ws += (size_t)512 * KP1 * 2;
    unsigned short* W4B    = (unsigned short*)ws;   ws += (size_t)NP4 * 512 * 2;
    unsigned short* W2T    = (unsigned short*)ws;   ws += (size_t)32 * 512 * 2;
    unsigned short* W3T    = (unsigned short*)ws;   ws += (size_t)512 * 32 * 2;
    unsigned short* h1B    = (unsigned short*)ws;   ws += (size_t)BATCH * 512 * 2;
    unsigned short* h2B    = (unsigned short*)ws;

    prep_kernel<<<Q_END, 256, 0, stream>>>(
        x, theta, W1, W2, W3, featsB, W1B, W2T, W3T);

    // GEMM1: feats[4096,832] @ W1 -> h1 (relu, bf16); 8-wave, BK=128+half tail
    gemm_mfma<8, 1, 2, 1, 1><<<512, 512, 0, stream>>>(
        featsB, W1B, b1, h1B, KP1, KP1, 512, 512, 7, 1, 8);
    // mlp_mid: h1 -> h2 (split-K thin pair) + W4 transpose; grid 256+104
    mlp_mid<<<360, 256, 0, stream>>>(h1B, W2T, W3T, b2, b3, W4, h2B, W4B);
    // GEMM4: h2[4096,512] @ W4 -> out (sigmoid, fp32); 8-wave, BK=64
    gemm_mfma<8, 1, 1, 2, 0><<<832, 512, 0, stream>>>(
        h2B, W4B, b4, out, 512, 512, FEATDIM, FEATDIM, 8, 0, 13);
}